// Round 14
// baseline (151.079 us; speedup 1.0000x reference)
//
#include <hip/hip_runtime.h>
#include <hip/hip_bf16.h>

// Difference3DCostVolume: cost[b,c,d,h,w] = l[b,c,h,w] - r[b,c,h,w-d] (w>=d), else 1.0
// Shapes: B=4, C=32, H=96, W=312, D=48. Output [B,C,D,H,W] f32 = 736 MB -> write-bound.
//
// R14 = R13 + ONE change: per-block dq-phase rotation (dq0 = (blk*5) % 12).
// All 256 blocks previously walked d=0..47 in lockstep from slice bases that are
// exact multiples of 1404 4KB-pages -> correlated DRAM bank/page phases across
// all concurrent write streams. Rotating each block's d-visit order (addresses
// unchanged, bijective cover) decorrelates the phases. Last untested memory-side
// variable; if null, ~150 us is the practical roofline for this op.
//
// Base design (R13): block = (bc, h-half of 48 rows); 256 blocks x 512 thr;
// LDS 120 KB; stage l,r once (31 MB total global reads); d-shift at LDS-read via
// hi/lo ds_read_b128 + literal word-select per RR=d&3; extents 59904 B contiguous;
// pad predicate from running w4 = m4 % 78 (step 44).

#define BB 4
#define CC 32
#define HH 96
#define WW 312
#define DD 48
#define CH 48                  // rows per block
#define NHALF (HH / CH)        // 2
#define CHF (CH * WW)          // 14976 floats per chunk
#define CH4 (CHF / 4)          // 3744 float4 per chunk
#define NT 512
#define NBLOCKS (BB * CC * NHALF) // 256
#define PAD4 16                // front pad (float4) >= max d/4 for rs underflow
#define W4STEP (NT % 78)       // 44

typedef float float4a __attribute__((ext_vector_type(4)));

__global__ __launch_bounds__(NT) void cost_volume_kernel(
    const float* __restrict__ l, const float* __restrict__ r,
    float* __restrict__ out) {
    const int blk = blockIdx.x;
    const int half = blk & 1;
    const int bc = blk >> 1;
    const int h0 = half * CH;
    const int tid = threadIdx.x;

    __shared__ float ls[CHF];                 // 59904 B
    __shared__ float rsm[PAD4 * 4 + CHF];     // 60160 B (front pad + data)

    float4a* ls4 = reinterpret_cast<float4a*>(ls);
    float4a* rs4 = reinterpret_cast<float4a*>(rsm);   // data at rs4[PAD4 + i]

    // ---- stage: straight contiguous copies (48 full rows each), all vec4.
    {
        const float4a* lsrc = reinterpret_cast<const float4a*>(
            l + ((size_t)bc * HH + h0) * WW);
        const float4a* rsrc = reinterpret_cast<const float4a*>(
            r + ((size_t)bc * HH + h0) * WW);
        for (int i = tid; i < CH4; i += NT) {
            ls4[i] = lsrc[i];
            rs4[PAD4 + i] = rsrc[i];
        }
    }
    __syncthreads();

    const int w40 = tid % 78;                 // w4 of this thread's first item
    float* obase = out + ((size_t)bc * DD * HH + h0) * (size_t)WW;

    // For d = 4*dq + RR: r window per lane j is chunk float 4*m4 + j - d ->
    //   lo = rs4[PAD4+m4-dq-1], hi = rs4[PAD4+m4-dq]; word select literal per RR.
    //   (b4 min = PAD4 - 11 = 5 > 0; first-row w<d lanes read garbage, pad-masked.)
#define BODY(RR, SELX, SELY, SELZ, SELW)                                     \
    {                                                                        \
        const int d = 4 * dq + (RR);                                         \
        float* od = obase + (size_t)d * (HH * WW);                           \
        int w4 = w40;                                                        \
        for (int m4 = tid; m4 < CH4; m4 += NT) {                             \
            const float4a a = ls4[m4];                                       \
            const int b4 = PAD4 + m4 - dq;                                   \
            const float4a hi = rs4[b4];                                      \
            const float4a lo = ((RR) == 0) ? hi : rs4[b4 - 1];               \
            const int w = 4 * w4;                                            \
            float4a v;                                                       \
            v.x = (w     >= d) ? (a.x - (SELX)) : 1.0f;                      \
            v.y = (w + 1 >= d) ? (a.y - (SELY)) : 1.0f;                      \
            v.z = (w + 2 >= d) ? (a.z - (SELZ)) : 1.0f;                      \
            v.w = (w + 3 >= d) ? (a.w - (SELW)) : 1.0f;                      \
            *reinterpret_cast<float4a*>(od + 4 * m4) = v;                    \
            w4 += W4STEP;                                                    \
            if (w4 >= 78) w4 -= 78;                                          \
        }                                                                    \
    }

    const int dq0 = (blk * 5) % 12;           // per-block phase rotation
    for (int i = 0; i < 12; ++i) {
        int dq = dq0 + i;
        if (dq >= 12) dq -= 12;               // dq = (dq0 + i) % 12
        BODY(0, hi.x, hi.y, hi.z, hi.w)
        BODY(1, lo.w, hi.x, hi.y, hi.z)
        BODY(2, lo.z, lo.w, hi.x, hi.y)
        BODY(3, lo.y, lo.z, lo.w, hi.x)
    }
#undef BODY
}

extern "C" void kernel_launch(void* const* d_in, const int* in_sizes, int n_in,
                              void* d_out, int out_size, void* d_ws, size_t ws_size,
                              hipStream_t stream) {
    const float* l = (const float*)d_in[0];
    const float* r = (const float*)d_in[1];
    float* out = (float*)d_out;
    cost_volume_kernel<<<dim3(NBLOCKS), dim3(NT), 0, stream>>>(l, r, out);
}